// Round 10
// baseline (182.203 us; speedup 1.0000x reference)
//
#include <hip/hip_runtime.h>

// TeamMovementModel R19: delete the aug MFMAs. R18 post-mortem: source-order
// interleave is not a lever (compiler reschedules); R14/R15/R17/R18 show the
// VALU phase is not critical either. Remaining levers: MFMA pipe + chain tail.
// The kt=4 aug MFMA tile is K=32 with only 3 nonzero entries (x0,x1,bias) --
// 4 MFMAs/wave/substep of ~9%-dense work at the END of every chain (exp2
// waits an MFMA latency). R19 folds x+bias into packed VALU instead:
//   xc[mi] = pk_fma(wi0v, x0, pk_fma(wi1v, x1, bsv))   (8 pk-fma/wave)
// acc-init movs carry xc (same count as before); chains end at kt=3 h-MFMA.
// xc depends only on static x_tab -> scheduler hoists it into bubbles.
// x-path now fp32 (was fp16-rounded) -> slightly closer to reference.
// Predicted: kernel ~98-102us, MfmaUtil ~20-21, VALUBusy ~34-36, VGPR ~132.

#define HDIM 128
#define TSTEPS 128
#define NPLAYER 1408
#define NSEQ 1472
#define NB 8
#define NBLK (NSEQ / NB)        // 184
#define NPBLK (NPLAYER / NB)    // 176
#define BSTR 168                // fp16 per B row (336 B stride, proven layout)
#define HSTR 132                // floats per hbuf row (16B-aligned, pad 4)

typedef _Float16 f16x8 __attribute__((ext_vector_type(8)));
typedef _Float16 f16x2 __attribute__((ext_vector_type(2)));
typedef __fp16   h16x2 __attribute__((ext_vector_type(2)));   // cvt_pkrtz return
typedef float    f32x4 __attribute__((ext_vector_type(4)));
typedef float    f32x2 __attribute__((ext_vector_type(2)));

#define LOG2E 1.4426950408889634f
#define K2    2.8853900817779268f   // 2*log2(e)

__device__ __forceinline__ f32x2 exp2v(f32x2 x) {
    return (f32x2){__builtin_amdgcn_exp2f(x[0]), __builtin_amdgcn_exp2f(x[1])};
}
__device__ __forceinline__ f32x2 rcpv(f32x2 x) {
    return (f32x2){__builtin_amdgcn_rcpf(x[0]), __builtin_amdgcn_rcpf(x[1])};
}

__global__ void __launch_bounds__(512)
__attribute__((amdgpu_waves_per_eu(2, 2)))
lstm_fc_kernel(const float* __restrict__ x_players, const float* __restrict__ x_ball,
               const float* __restrict__ p_w_ih, const float* __restrict__ p_w_hh,
               const float* __restrict__ p_b_ih, const float* __restrict__ p_b_hh,
               const float* __restrict__ b_w_ih, const float* __restrict__ b_w_hh,
               const float* __restrict__ b_b_ih, const float* __restrict__ b_b_hh,
               const float* __restrict__ fc_w, const float* __restrict__ fc_b,
               float* __restrict__ out)
{
    const int tid  = threadIdx.x;
    const int blk  = blockIdx.x;          // 0..183; 176..183 ball
    const int w    = tid >> 6;            // wave -> h-rows [16w, 16w+16)
    const int lane = tid & 63;
    const int nn   = lane & 15;           // MFMA n (col)
    const int q    = lane >> 4;           // MFMA quad

    const bool ball = (blk >= NPBLK);
    const float* w_ih = ball ? b_w_ih : p_w_ih;
    const float* w_hh = ball ? b_w_hh : p_w_hh;
    const float* bih  = ball ? b_b_ih : p_b_ih;
    const float* bhh  = ball ? b_b_hh : p_b_hh;
    const float* xg   = ball ? (x_ball    + (size_t)(blk - NPBLK) * NB * TSTEPS * 2)
                             : (x_players + (size_t)blk * NB * TSTEPS * 2);

    __shared__ __align__(16) _Float16 b_sh[2][NB * BSTR];
    __shared__ __align__(8)  f32x2 x_tab[TSTEPS * NB];   // [t][seq], f32 pairs
    __shared__ __align__(16) float hbuf[NB * HSTR];      // final h, fp32
    __shared__ float vout[NB * 40];                      // ball-path per-batch fc part

    // zero h double-buffers (buf0 = h(-1) = 0; buf1 fully overwritten each step)
    for (int i = tid; i < 2 * NB * BSTR / 2; i += 512)
        ((int*)b_sh)[i] = 0;
    // static f32 x table (coalesced: t fastest)
    for (int i = tid; i < TSTEPS * NB; i += 512) {
        const int sq = i >> 7, t = i & 127;
        const float2 xv2 = ((const float2*)xg)[sq * TSTEPS + t];
        x_tab[t * NB + sq] = (f32x2){xv2.x, xv2.y};
    }

    // ---- A fragments (pre-scaled): gate mi, row r = mi*128 + 16w + nn.
    // a[j] = A[m=lane&15][k = 32kt + 8q + j]; K = 128 (h only, no aug tile)
    const int rowoff = (nn < 8) ? 0 : 2;        // which acc regs this lane keeps
    f16x8 afr[4][4];
    f32x2 wi0v[4], wi1v[4], bsv[4];             // per-lane x-weights/bias, packed
    #pragma unroll
    for (int mi = 0; mi < 4; ++mi) {
        const float sc = (mi == 2) ? K2 : LOG2E;   // g gate gets 2*log2e
        const int r = mi * HDIM + w * 16 + nn;
        const float* wr = w_hh + (size_t)r * HDIM;
        #pragma unroll
        for (int kt = 0; kt < 4; ++kt) {
            const float* p = wr + kt * 32 + q * 8;
            f16x8 a8;
            #pragma unroll
            for (int j = 0; j < 8; ++j) a8[j] = (_Float16)(sc * p[j]);
            afr[mi][kt] = a8;
        }
        // per-lane x-weights + bias for the 2 kept rows (4q+rowoff, +1)
        const int rb = mi * HDIM + w * 16 + 4 * q + rowoff;
        wi0v[mi] = (f32x2){sc * w_ih[2 * rb],     sc * w_ih[2 * (rb + 1)]};
        wi1v[mi] = (f32x2){sc * w_ih[2 * rb + 1], sc * w_ih[2 * (rb + 1) + 1]};
        bsv[mi]  = (f32x2){sc * (bih[rb] + bhh[rb]),
                           sc * (bih[rb + 1] + bhh[rb + 1])};
    }

    const int colh = nn & 7;                    // owned seq col (dup across nn^8)
    const int hrow = w * 16 + 4 * q + rowoff;   // first of 2 owned h-rows
    f32x2 cc = {0.f, 0.f};                      // c kept in 2*log2e scale
    f32x2 hh = {0.f, 0.f};

    __syncthreads();

    auto substep = [&](int s, const _Float16* bc, _Float16* bn, bool last) {
        f16x8 bfr[4];
        const _Float16* bp = bc + colh * BSTR + q * 8;
        #pragma unroll
        for (int kt = 0; kt < 4; ++kt)
            bfr[kt] = *(const f16x8*)(bp + kt * 32);
        const f32x2 xv = x_tab[s * NB + colh];   // {x0, x1}, h-independent

        // x+bias term, packed over the 2 kept rows; hoistable into bubbles
        f32x2 xc[4];
        #pragma unroll
        for (int mi = 0; mi < 4; ++mi) {
            const f32x2 x0s = {xv[0], xv[0]};
            const f32x2 x1s = {xv[1], xv[1]};
            f32x2 t = bsv[mi];
            t = wi1v[mi] * x1s + t;
            xc[mi] = wi0v[mi] * x0s + t;
        }

        f32x4 acc[4];
        #pragma unroll
        for (int mi = 0; mi < 4; ++mi)
            acc[mi] = (f32x4){xc[mi][0], xc[mi][1], xc[mi][0], xc[mi][1]};
        #pragma unroll
        for (int kt = 0; kt < 4; ++kt)
            #pragma unroll
            for (int mi = 0; mi < 4; ++mi)
                acc[mi] = __builtin_amdgcn_mfma_f32_16x16x32_f16(afr[mi][kt], bfr[kt], acc[mi], 0, 0, 0);

        // B cols duplicated -> lane nn>=8's own regs {2,3} are rows 4q+2,4q+3
        f32x2 u[4];
        #pragma unroll
        for (int mi = 0; mi < 4; ++mi) {
            const f32x2 lo = (f32x2){acc[mi][0], acc[mi][1]};
            const f32x2 hi = (f32x2){acc[mi][2], acc[mi][3]};
            u[mi] = (nn < 8) ? lo : hi;
        }

        // u pre-scaled: [0]=i',[1]=f',[3]=o' (log2e); [2]=g' (2*log2e)
        const f32x2 one = {1.0f, 1.0f};
        const f32x2 A = exp2v(-u[0]);
        const f32x2 F = exp2v(-u[1]);
        const f32x2 G = exp2v( u[2]);
        const f32x2 O = exp2v(-u[3]);
        // c' = f*c' + K2*i*g  ==  (c'*dA + K2*(G-1)*e) * rcp(dA*e),
        // dA = (1+A)(G+1), e = 1+F   (one rcp; exact rewrite)
        const f32x2 dA = (one + A) * (G + one);
        const f32x2 t  = G * K2 - K2;
        const f32x2 e  = one + F;
        const f32x2 rd = rcpv(dA * e);
        cc = (cc * dA + t * e) * rd;
        const f32x2 C = exp2v(cc);
        // h = o*tanh(c) = (C-1) * rcp((C+1)(1+O))
        const f32x2 rr = rcpv((C + one) * (one + O));
        hh = (C - one) * rr;

        if (!last) {
            // packed RTZ convert: 1 inst vs cvt+cvt+pack (4B-aligned: hrow even)
            *(h16x2*)&bn[colh * BSTR + hrow] = __builtin_amdgcn_cvt_pkrtz(hh[0], hh[1]);
            __syncthreads();
        }
    };

    _Float16* b0 = &b_sh[0][0];
    _Float16* b1 = &b_sh[1][0];
    #pragma unroll 1
    for (int it = 0; it < TSTEPS / 2 - 1; ++it) {   // steps 0..125
        substep(2 * it,     b0, b1, false);
        substep(2 * it + 1, b1, b0, false);
        // loop-carried AGPR pins: block rematerialization (R1..R5 failure mode)
        asm volatile("" : "+a"(afr[0][0]), "+a"(afr[0][1]), "+a"(afr[0][2]), "+a"(afr[0][3]));
        asm volatile("" : "+a"(afr[1][0]), "+a"(afr[1][1]), "+a"(afr[1][2]), "+a"(afr[1][3]));
        asm volatile("" : "+a"(afr[2][0]), "+a"(afr[2][1]), "+a"(afr[2][2]), "+a"(afr[2][3]));
        asm volatile("" : "+a"(afr[3][0]), "+a"(afr[3][1]), "+a"(afr[3][2]), "+a"(afr[3][3]));
    }
    substep(126, b0, b1, false);
    substep(127, b1, b0, true);    // peeled: no h-write, no barrier

    // ---- final h -> LDS (fp32), then fused FC epilogue ----
    hbuf[colh * HSTR + hrow]     = hh[0];
    hbuf[colh * HSTR + hrow + 1] = hh[1];
    __syncthreads();

    if (!ball) {
        // player part: out[gp*40+row] += fc_b[row] + fc_w[row, 0:128] . h(gp)
        for (int o = tid; o < NB * 40; o += 512) {
            const int j = o / 40, row = o - j * 40;
            const float* wr = fc_w + (size_t)row * 2 * HDIM;        // cols 0..127
            const float* hp = &hbuf[j * HSTR];
            float a0 = fc_b[row], a1 = 0.f, a2 = 0.f, a3 = 0.f;
            #pragma unroll
            for (int k = 0; k < HDIM; k += 4) {
                float4 wv = *(const float4*)(wr + k);
                float4 hv = *(const float4*)(hp + k);
                a0 = __builtin_fmaf(wv.x, hv.x, a0);
                a1 = __builtin_fmaf(wv.y, hv.y, a1);
                a2 = __builtin_fmaf(wv.z, hv.z, a2);
                a3 = __builtin_fmaf(wv.w, hv.w, a3);
            }
            atomicAdd(&out[(size_t)(NB * blk + j) * 40 + row], (a0 + a1) + (a2 + a3));
        }
    } else {
        // ball part: v[c][row] = fc_w[row, 128:256] . ball_h(batch), then
        // broadcast-add to the batch's 22 players.
        for (int o = tid; o < NB * 40; o += 512) {
            const int c = o / 40, row = o - c * 40;
            const float* wr = fc_w + (size_t)row * 2 * HDIM + HDIM;  // cols 128..255
            const float* hp = &hbuf[c * HSTR];
            float a0 = 0.f, a1 = 0.f, a2 = 0.f, a3 = 0.f;
            #pragma unroll
            for (int k = 0; k < HDIM; k += 4) {
                float4 wv = *(const float4*)(wr + k);
                float4 hv = *(const float4*)(hp + k);
                a0 = __builtin_fmaf(wv.x, hv.x, a0);
                a1 = __builtin_fmaf(wv.y, hv.y, a1);
                a2 = __builtin_fmaf(wv.z, hv.z, a2);
                a3 = __builtin_fmaf(wv.w, hv.w, a3);
            }
            vout[c * 40 + row] = (a0 + a1) + (a2 + a3);
        }
        __syncthreads();
        const int base_batch = (blk - NPBLK) * NB;
        for (int o = tid; o < NB * 22 * 40; o += 512) {
            const int c = o / 880, rem = o - c * 880;
            const int p = rem / 40, row = rem - p * 40;
            atomicAdd(&out[(size_t)((base_batch + c) * 22 + p) * 40 + row],
                      vout[c * 40 + row]);
        }
    }
}

extern "C" void kernel_launch(void* const* d_in, const int* in_sizes, int n_in,
                              void* d_out, int out_size, void* d_ws, size_t ws_size,
                              hipStream_t stream) {
    const float* x_players = (const float*)d_in[0];
    const float* x_ball    = (const float*)d_in[1];
    const float* p_w_ih    = (const float*)d_in[2];
    const float* p_w_hh    = (const float*)d_in[3];
    const float* p_b_ih    = (const float*)d_in[4];
    const float* p_b_hh    = (const float*)d_in[5];
    const float* b_w_ih    = (const float*)d_in[6];
    const float* b_w_hh    = (const float*)d_in[7];
    const float* b_b_ih    = (const float*)d_in[8];
    const float* b_b_hh    = (const float*)d_in[9];
    const float* fc_w      = (const float*)d_in[10];
    const float* fc_b      = (const float*)d_in[11];

    // zero the output: both block types accumulate into it atomically
    hipMemsetAsync(d_out, 0, (size_t)out_size * sizeof(float), stream);

    lstm_fc_kernel<<<dim3(NBLK), dim3(512), 0, stream>>>(
        x_players, x_ball, p_w_ih, p_w_hh, p_b_ih, p_b_hh,
        b_w_ih, b_w_hh, b_b_ih, b_b_hh, fc_w, fc_b, (float*)d_out);
}

// Round 11
// 181.487 us; speedup vs baseline: 1.0039x; 1.0039x over previous
//
#include <hip/hip_runtime.h>

// TeamMovementModel R20: R19 with the load-order bug fixed.
// R19 post-mortem: removing the aug MFMAs regressed (104->119.6us) NOT because
// of the VALU fold, but because acc-init depended on the x_tab read which was
// issued LAST -> the wait before acc-init was lgkmcnt(0), draining all 4 bfr
// ds_reads and exposing the ~120cyc LDS latency every substep (in R16b, x
// feeds only the final aug MFMA, so its wait lands late).
// R20: x_tab read issued FIRST, xc computed immediately (overlaps in-flight
// bfr reads), bfr reads after, acc-init, then kt MFMAs (kt=0 waits bfr[0]
// only, as in R16b). Keeps R19's gains: -4 MFMAs/wave/substep (-64 pipe
// cyc/SIMD), one-MFMA-shorter chain tail, x-path in f32.
// Predicted: kernel ~97-101us, MfmaUtil ~19-21, VALUBusy ~36-38, VGPR ~110.

#define HDIM 128
#define TSTEPS 128
#define NPLAYER 1408
#define NSEQ 1472
#define NB 8
#define NBLK (NSEQ / NB)        // 184
#define NPBLK (NPLAYER / NB)    // 176
#define BSTR 168                // fp16 per B row (336 B stride, proven layout)
#define HSTR 132                // floats per hbuf row (16B-aligned, pad 4)

typedef _Float16 f16x8 __attribute__((ext_vector_type(8)));
typedef _Float16 f16x2 __attribute__((ext_vector_type(2)));
typedef __fp16   h16x2 __attribute__((ext_vector_type(2)));   // cvt_pkrtz return
typedef float    f32x4 __attribute__((ext_vector_type(4)));
typedef float    f32x2 __attribute__((ext_vector_type(2)));

#define LOG2E 1.4426950408889634f
#define K2    2.8853900817779268f   // 2*log2(e)

__device__ __forceinline__ f32x2 exp2v(f32x2 x) {
    return (f32x2){__builtin_amdgcn_exp2f(x[0]), __builtin_amdgcn_exp2f(x[1])};
}
__device__ __forceinline__ f32x2 rcpv(f32x2 x) {
    return (f32x2){__builtin_amdgcn_rcpf(x[0]), __builtin_amdgcn_rcpf(x[1])};
}

__global__ void __launch_bounds__(512)
__attribute__((amdgpu_waves_per_eu(2, 2)))
lstm_fc_kernel(const float* __restrict__ x_players, const float* __restrict__ x_ball,
               const float* __restrict__ p_w_ih, const float* __restrict__ p_w_hh,
               const float* __restrict__ p_b_ih, const float* __restrict__ p_b_hh,
               const float* __restrict__ b_w_ih, const float* __restrict__ b_w_hh,
               const float* __restrict__ b_b_ih, const float* __restrict__ b_b_hh,
               const float* __restrict__ fc_w, const float* __restrict__ fc_b,
               float* __restrict__ out)
{
    const int tid  = threadIdx.x;
    const int blk  = blockIdx.x;          // 0..183; 176..183 ball
    const int w    = tid >> 6;            // wave -> h-rows [16w, 16w+16)
    const int lane = tid & 63;
    const int nn   = lane & 15;           // MFMA n (col)
    const int q    = lane >> 4;           // MFMA quad

    const bool ball = (blk >= NPBLK);
    const float* w_ih = ball ? b_w_ih : p_w_ih;
    const float* w_hh = ball ? b_w_hh : p_w_hh;
    const float* bih  = ball ? b_b_ih : p_b_ih;
    const float* bhh  = ball ? b_b_hh : p_b_hh;
    const float* xg   = ball ? (x_ball    + (size_t)(blk - NPBLK) * NB * TSTEPS * 2)
                             : (x_players + (size_t)blk * NB * TSTEPS * 2);

    __shared__ __align__(16) _Float16 b_sh[2][NB * BSTR];
    __shared__ __align__(8)  f32x2 x_tab[TSTEPS * NB];   // [t][seq], f32 pairs
    __shared__ __align__(16) float hbuf[NB * HSTR];      // final h, fp32
    __shared__ float vout[NB * 40];                      // ball-path per-batch fc part

    // zero h double-buffers (buf0 = h(-1) = 0; buf1 fully overwritten each step)
    for (int i = tid; i < 2 * NB * BSTR / 2; i += 512)
        ((int*)b_sh)[i] = 0;
    // static f32 x table (coalesced: t fastest)
    for (int i = tid; i < TSTEPS * NB; i += 512) {
        const int sq = i >> 7, t = i & 127;
        const float2 xv2 = ((const float2*)xg)[sq * TSTEPS + t];
        x_tab[t * NB + sq] = (f32x2){xv2.x, xv2.y};
    }

    // ---- A fragments (pre-scaled): gate mi, row r = mi*128 + 16w + nn.
    // a[j] = A[m=lane&15][k = 32kt + 8q + j]; K = 128 (h only, no aug tile)
    const int rowoff = (nn < 8) ? 0 : 2;        // which acc regs this lane keeps
    f16x8 afr[4][4];
    f32x2 wi0v[4], wi1v[4], bsv[4];             // per-lane x-weights/bias, packed
    #pragma unroll
    for (int mi = 0; mi < 4; ++mi) {
        const float sc = (mi == 2) ? K2 : LOG2E;   // g gate gets 2*log2e
        const int r = mi * HDIM + w * 16 + nn;
        const float* wr = w_hh + (size_t)r * HDIM;
        #pragma unroll
        for (int kt = 0; kt < 4; ++kt) {
            const float* p = wr + kt * 32 + q * 8;
            f16x8 a8;
            #pragma unroll
            for (int j = 0; j < 8; ++j) a8[j] = (_Float16)(sc * p[j]);
            afr[mi][kt] = a8;
        }
        // per-lane x-weights + bias for the 2 kept rows (4q+rowoff, +1)
        const int rb = mi * HDIM + w * 16 + 4 * q + rowoff;
        wi0v[mi] = (f32x2){sc * w_ih[2 * rb],     sc * w_ih[2 * (rb + 1)]};
        wi1v[mi] = (f32x2){sc * w_ih[2 * rb + 1], sc * w_ih[2 * (rb + 1) + 1]};
        bsv[mi]  = (f32x2){sc * (bih[rb] + bhh[rb]),
                           sc * (bih[rb + 1] + bhh[rb + 1])};
    }

    const int colh = nn & 7;                    // owned seq col (dup across nn^8)
    const int hrow = w * 16 + 4 * q + rowoff;   // first of 2 owned h-rows
    f32x2 cc = {0.f, 0.f};                      // c kept in 2*log2e scale
    f32x2 hh = {0.f, 0.f};

    __syncthreads();

    auto substep = [&](int s, const _Float16* bc, _Float16* bn, bool last) {
        // x FIRST: its lgkm wait must precede (not drain) the bfr reads.
        const f32x2 xv = x_tab[s * NB + colh];   // {x0, x1}, h-independent
        // xc computed right away: overlaps the bfr ds_read latency.
        f32x2 xc[4];
        #pragma unroll
        for (int mi = 0; mi < 4; ++mi) {
            const f32x2 x0s = {xv[0], xv[0]};
            const f32x2 x1s = {xv[1], xv[1]};
            f32x2 t = bsv[mi];
            t = wi1v[mi] * x1s + t;
            xc[mi] = wi0v[mi] * x0s + t;
        }

        f16x8 bfr[4];
        const _Float16* bp = bc + colh * BSTR + q * 8;
        #pragma unroll
        for (int kt = 0; kt < 4; ++kt)
            bfr[kt] = *(const f16x8*)(bp + kt * 32);

        f32x4 acc[4];
        #pragma unroll
        for (int mi = 0; mi < 4; ++mi)
            acc[mi] = (f32x4){xc[mi][0], xc[mi][1], xc[mi][0], xc[mi][1]};
        #pragma unroll
        for (int kt = 0; kt < 4; ++kt)
            #pragma unroll
            for (int mi = 0; mi < 4; ++mi)
                acc[mi] = __builtin_amdgcn_mfma_f32_16x16x32_f16(afr[mi][kt], bfr[kt], acc[mi], 0, 0, 0);

        // B cols duplicated -> lane nn>=8's own regs {2,3} are rows 4q+2,4q+3
        f32x2 u[4];
        #pragma unroll
        for (int mi = 0; mi < 4; ++mi) {
            const f32x2 lo = (f32x2){acc[mi][0], acc[mi][1]};
            const f32x2 hi = (f32x2){acc[mi][2], acc[mi][3]};
            u[mi] = (nn < 8) ? lo : hi;
        }

        // u pre-scaled: [0]=i',[1]=f',[3]=o' (log2e); [2]=g' (2*log2e)
        const f32x2 one = {1.0f, 1.0f};
        const f32x2 A = exp2v(-u[0]);
        const f32x2 F = exp2v(-u[1]);
        const f32x2 G = exp2v( u[2]);
        const f32x2 O = exp2v(-u[3]);
        // c' = f*c' + K2*i*g  ==  (c'*dA + K2*(G-1)*e) * rcp(dA*e),
        // dA = (1+A)(G+1), e = 1+F   (one rcp; exact rewrite)
        const f32x2 dA = (one + A) * (G + one);
        const f32x2 t  = G * K2 - K2;
        const f32x2 e  = one + F;
        const f32x2 rd = rcpv(dA * e);
        cc = (cc * dA + t * e) * rd;
        const f32x2 C = exp2v(cc);
        // h = o*tanh(c) = (C-1) * rcp((C+1)(1+O))
        const f32x2 rr = rcpv((C + one) * (one + O));
        hh = (C - one) * rr;

        if (!last) {
            // packed RTZ convert: 1 inst vs cvt+cvt+pack (4B-aligned: hrow even)
            *(h16x2*)&bn[colh * BSTR + hrow] = __builtin_amdgcn_cvt_pkrtz(hh[0], hh[1]);
            __syncthreads();
        }
    };

    _Float16* b0 = &b_sh[0][0];
    _Float16* b1 = &b_sh[1][0];
    #pragma unroll 1
    for (int it = 0; it < TSTEPS / 2 - 1; ++it) {   // steps 0..125
        substep(2 * it,     b0, b1, false);
        substep(2 * it + 1, b1, b0, false);
        // loop-carried AGPR pins: block rematerialization (R1..R5 failure mode)
        asm volatile("" : "+a"(afr[0][0]), "+a"(afr[0][1]), "+a"(afr[0][2]), "+a"(afr[0][3]));
        asm volatile("" : "+a"(afr[1][0]), "+a"(afr[1][1]), "+a"(afr[1][2]), "+a"(afr[1][3]));
        asm volatile("" : "+a"(afr[2][0]), "+a"(afr[2][1]), "+a"(afr[2][2]), "+a"(afr[2][3]));
        asm volatile("" : "+a"(afr[3][0]), "+a"(afr[3][1]), "+a"(afr[3][2]), "+a"(afr[3][3]));
    }
    substep(126, b0, b1, false);
    substep(127, b1, b0, true);    // peeled: no h-write, no barrier

    // ---- final h -> LDS (fp32), then fused FC epilogue ----
    hbuf[colh * HSTR + hrow]     = hh[0];
    hbuf[colh * HSTR + hrow + 1] = hh[1];
    __syncthreads();

    if (!ball) {
        // player part: out[gp*40+row] += fc_b[row] + fc_w[row, 0:128] . h(gp)
        for (int o = tid; o < NB * 40; o += 512) {
            const int j = o / 40, row = o - j * 40;
            const float* wr = fc_w + (size_t)row * 2 * HDIM;        // cols 0..127
            const float* hp = &hbuf[j * HSTR];
            float a0 = fc_b[row], a1 = 0.f, a2 = 0.f, a3 = 0.f;
            #pragma unroll
            for (int k = 0; k < HDIM; k += 4) {
                float4 wv = *(const float4*)(wr + k);
                float4 hv = *(const float4*)(hp + k);
                a0 = __builtin_fmaf(wv.x, hv.x, a0);
                a1 = __builtin_fmaf(wv.y, hv.y, a1);
                a2 = __builtin_fmaf(wv.z, hv.z, a2);
                a3 = __builtin_fmaf(wv.w, hv.w, a3);
            }
            atomicAdd(&out[(size_t)(NB * blk + j) * 40 + row], (a0 + a1) + (a2 + a3));
        }
    } else {
        // ball part: v[c][row] = fc_w[row, 128:256] . ball_h(batch), then
        // broadcast-add to the batch's 22 players.
        for (int o = tid; o < NB * 40; o += 512) {
            const int c = o / 40, row = o - c * 40;
            const float* wr = fc_w + (size_t)row * 2 * HDIM + HDIM;  // cols 128..255
            const float* hp = &hbuf[c * HSTR];
            float a0 = 0.f, a1 = 0.f, a2 = 0.f, a3 = 0.f;
            #pragma unroll
            for (int k = 0; k < HDIM; k += 4) {
                float4 wv = *(const float4*)(wr + k);
                float4 hv = *(const float4*)(hp + k);
                a0 = __builtin_fmaf(wv.x, hv.x, a0);
                a1 = __builtin_fmaf(wv.y, hv.y, a1);
                a2 = __builtin_fmaf(wv.z, hv.z, a2);
                a3 = __builtin_fmaf(wv.w, hv.w, a3);
            }
            vout[c * 40 + row] = (a0 + a1) + (a2 + a3);
        }
        __syncthreads();
        const int base_batch = (blk - NPBLK) * NB;
        for (int o = tid; o < NB * 22 * 40; o += 512) {
            const int c = o / 880, rem = o - c * 880;
            const int p = rem / 40, row = rem - p * 40;
            atomicAdd(&out[(size_t)((base_batch + c) * 22 + p) * 40 + row],
                      vout[c * 40 + row]);
        }
    }
}

extern "C" void kernel_launch(void* const* d_in, const int* in_sizes, int n_in,
                              void* d_out, int out_size, void* d_ws, size_t ws_size,
                              hipStream_t stream) {
    const float* x_players = (const float*)d_in[0];
    const float* x_ball    = (const float*)d_in[1];
    const float* p_w_ih    = (const float*)d_in[2];
    const float* p_w_hh    = (const float*)d_in[3];
    const float* p_b_ih    = (const float*)d_in[4];
    const float* p_b_hh    = (const float*)d_in[5];
    const float* b_w_ih    = (const float*)d_in[6];
    const float* b_w_hh    = (const float*)d_in[7];
    const float* b_b_ih    = (const float*)d_in[8];
    const float* b_b_hh    = (const float*)d_in[9];
    const float* fc_w      = (const float*)d_in[10];
    const float* fc_b      = (const float*)d_in[11];

    // zero the output: both block types accumulate into it atomically
    hipMemsetAsync(d_out, 0, (size_t)out_size * sizeof(float), stream);

    lstm_fc_kernel<<<dim3(NBLK), dim3(512), 0, stream>>>(
        x_players, x_ball, p_w_ih, p_w_hh, p_b_ih, p_b_hh,
        b_w_ih, b_w_hh, b_b_ih, b_b_hh, fc_w, fc_b, (float*)d_out);
}

// Round 12
// 166.111 us; speedup vs baseline: 1.0969x; 1.0926x over previous
//
#include <hip/hip_runtime.h>

// TeamMovementModel R21: aug-MFMA removal, third (final) variant.
// R19/R20 post-mortem: both regressed ~15% because the first MFMA's C-input
// (acc-init) depended on a per-substep ds_read+VALU chain (xc). Three-strike
// rule confirmed (R14/R15/R19/R20): MFMA C-input MUST be loop-invariant.
// R21 keeps R16b's invariant exactly - acc-init = bias constants - and moves
// the x contribution to AFTER the select:
//   u[mi] = select(acc[mi]) + xc[mi],  xc = pk_fma(wi0v,x0, pk_fma(wi1v,x1))
// xc depends only on static x_tab -> its ds_read latency hides under the 16
// MFMAs; chain tail +1 pk_add (~2cyc) but -1 MFMA (-8cyc) and pipe -64cyc.
// Diffs vs measured-best R16b (104.2us): (1) no aug MFMA/bx, (2) wi0v/wi1v
// per-lane f32x2 + 8 pk_fma, (3) u += xc post-select. x_tab stays f16x2.
// Predicted: kernel ~100-102us, MfmaUtil ~19-20, VALUBusy ~35-37, VGPR ~135.
// Abort criterion: >=104us -> revert to R16b as final.

#define HDIM 128
#define TSTEPS 128
#define NPLAYER 1408
#define NSEQ 1472
#define NB 8
#define NBLK (NSEQ / NB)        // 184
#define NPBLK (NPLAYER / NB)    // 176
#define BSTR 168                // fp16 per B row (336 B stride, proven layout)
#define HSTR 132                // floats per hbuf row (16B-aligned, pad 4)

typedef _Float16 f16x8 __attribute__((ext_vector_type(8)));
typedef _Float16 f16x2 __attribute__((ext_vector_type(2)));
typedef __fp16   h16x2 __attribute__((ext_vector_type(2)));   // cvt_pkrtz return
typedef float    f32x4 __attribute__((ext_vector_type(4)));
typedef float    f32x2 __attribute__((ext_vector_type(2)));

#define LOG2E 1.4426950408889634f
#define K2    2.8853900817779268f   // 2*log2(e)

__device__ __forceinline__ f32x2 exp2v(f32x2 x) {
    return (f32x2){__builtin_amdgcn_exp2f(x[0]), __builtin_amdgcn_exp2f(x[1])};
}
__device__ __forceinline__ f32x2 rcpv(f32x2 x) {
    return (f32x2){__builtin_amdgcn_rcpf(x[0]), __builtin_amdgcn_rcpf(x[1])};
}

__global__ void __launch_bounds__(512)
__attribute__((amdgpu_waves_per_eu(2, 2)))
lstm_fc_kernel(const float* __restrict__ x_players, const float* __restrict__ x_ball,
               const float* __restrict__ p_w_ih, const float* __restrict__ p_w_hh,
               const float* __restrict__ p_b_ih, const float* __restrict__ p_b_hh,
               const float* __restrict__ b_w_ih, const float* __restrict__ b_w_hh,
               const float* __restrict__ b_b_ih, const float* __restrict__ b_b_hh,
               const float* __restrict__ fc_w, const float* __restrict__ fc_b,
               float* __restrict__ out)
{
    const int tid  = threadIdx.x;
    const int blk  = blockIdx.x;          // 0..183; 176..183 ball
    const int w    = tid >> 6;            // wave -> h-rows [16w, 16w+16)
    const int lane = tid & 63;
    const int nn   = lane & 15;           // MFMA n (col)
    const int q    = lane >> 4;           // MFMA quad

    const bool ball = (blk >= NPBLK);
    const float* w_ih = ball ? b_w_ih : p_w_ih;
    const float* w_hh = ball ? b_w_hh : p_w_hh;
    const float* bih  = ball ? b_b_ih : p_b_ih;
    const float* bhh  = ball ? b_b_hh : p_b_hh;
    const float* xg   = ball ? (x_ball    + (size_t)(blk - NPBLK) * NB * TSTEPS * 2)
                             : (x_players + (size_t)blk * NB * TSTEPS * 2);

    __shared__ __align__(16) _Float16 b_sh[2][NB * BSTR];
    __shared__ __align__(4)  f16x2 x_tab[TSTEPS * NB];   // [t][seq], fp16 pairs
    __shared__ __align__(16) float hbuf[NB * HSTR];      // final h, fp32
    __shared__ float vout[NB * 40];                      // ball-path per-batch fc part

    // zero h double-buffers (buf0 = h(-1) = 0; buf1 fully overwritten each step)
    for (int i = tid; i < 2 * NB * BSTR / 2; i += 512)
        ((int*)b_sh)[i] = 0;
    // static fp16 x table (coalesced: t fastest)
    for (int i = tid; i < TSTEPS * NB; i += 512) {
        const int sq = i >> 7, t = i & 127;
        const float2 xv2 = ((const float2*)xg)[sq * TSTEPS + t];
        x_tab[t * NB + sq] = (f16x2){(_Float16)xv2.x, (_Float16)xv2.y};
    }

    // ---- A fragments (pre-scaled): gate mi, row r = mi*128 + 16w + nn.
    // a[j] = A[m=lane&15][k = 32kt + 8q + j]; K = 128 (h only, no aug tile)
    const int rowoff = (nn < 8) ? 0 : 2;        // which acc regs this lane keeps
    f16x8 afr[4][4];
    float bias0[4], bias1[4];                   // loop-invariant C-init (R16b rule)
    f32x2 wi0v[4], wi1v[4];                     // per-lane x-weights, packed
    #pragma unroll
    for (int mi = 0; mi < 4; ++mi) {
        const float sc = (mi == 2) ? K2 : LOG2E;   // g gate gets 2*log2e
        const int r = mi * HDIM + w * 16 + nn;
        const float* wr = w_hh + (size_t)r * HDIM;
        #pragma unroll
        for (int kt = 0; kt < 4; ++kt) {
            const float* p = wr + kt * 32 + q * 8;
            f16x8 a8;
            #pragma unroll
            for (int j = 0; j < 8; ++j) a8[j] = (_Float16)(sc * p[j]);
            afr[mi][kt] = a8;
        }
        // bias + x-weights for this lane's kept rows (4q+rowoff, +1), pre-scaled
        const int rb = mi * HDIM + w * 16 + 4 * q + rowoff;
        bias0[mi] = sc * (bih[rb] + bhh[rb]);
        bias1[mi] = sc * (bih[rb + 1] + bhh[rb + 1]);
        wi0v[mi] = (f32x2){sc * w_ih[2 * rb],     sc * w_ih[2 * (rb + 1)]};
        wi1v[mi] = (f32x2){sc * w_ih[2 * rb + 1], sc * w_ih[2 * (rb + 1) + 1]};
    }

    const int colh = nn & 7;                    // owned seq col (dup across nn^8)
    const int hrow = w * 16 + 4 * q + rowoff;   // first of 2 owned h-rows
    f32x2 cc = {0.f, 0.f};                      // c kept in 2*log2e scale
    f32x2 hh = {0.f, 0.f};

    __syncthreads();

    auto substep = [&](int s, const _Float16* bc, _Float16* bn, bool last) {
        f16x8 bfr[4];
        const _Float16* bp = bc + colh * BSTR + q * 8;
        #pragma unroll
        for (int kt = 0; kt < 4; ++kt)
            bfr[kt] = *(const f16x8*)(bp + kt * 32);
        // x for this step: broadcast ds_read_b32; feeds only the POST-select
        // add, so its latency hides under the 16-MFMA block.
        const f16x2 xv = x_tab[s * NB + colh];
        const float x0 = (float)xv[0], x1 = (float)xv[1];
        f32x2 xc[4];
        #pragma unroll
        for (int mi = 0; mi < 4; ++mi) {
            const f32x2 x0s = {x0, x0};
            const f32x2 x1s = {x1, x1};
            xc[mi] = wi0v[mi] * x0s + wi1v[mi] * x1s;
        }

        // C-init = loop-invariant bias constants (the proven R16b pattern)
        f32x4 acc[4];
        #pragma unroll
        for (int mi = 0; mi < 4; ++mi)
            acc[mi] = (f32x4){bias0[mi], bias1[mi], bias0[mi], bias1[mi]};
        #pragma unroll
        for (int kt = 0; kt < 4; ++kt)
            #pragma unroll
            for (int mi = 0; mi < 4; ++mi)
                acc[mi] = __builtin_amdgcn_mfma_f32_16x16x32_f16(afr[mi][kt], bfr[kt], acc[mi], 0, 0, 0);

        // B cols duplicated -> lane nn>=8's own regs {2,3} are rows 4q+2,4q+3;
        // x joins after the select (u = Whh.h + bias + Wih.x)
        f32x2 u[4];
        #pragma unroll
        for (int mi = 0; mi < 4; ++mi) {
            const f32x2 lo = (f32x2){acc[mi][0], acc[mi][1]};
            const f32x2 hi = (f32x2){acc[mi][2], acc[mi][3]};
            u[mi] = ((nn < 8) ? lo : hi) + xc[mi];
        }

        // u pre-scaled: [0]=i',[1]=f',[3]=o' (log2e); [2]=g' (2*log2e)
        const f32x2 one = {1.0f, 1.0f};
        const f32x2 A = exp2v(-u[0]);
        const f32x2 F = exp2v(-u[1]);
        const f32x2 G = exp2v( u[2]);
        const f32x2 O = exp2v(-u[3]);
        // c' = f*c' + K2*i*g  ==  (c'*dA + K2*(G-1)*e) * rcp(dA*e),
        // dA = (1+A)(G+1), e = 1+F   (one rcp; exact rewrite)
        const f32x2 dA = (one + A) * (G + one);
        const f32x2 t  = G * K2 - K2;
        const f32x2 e  = one + F;
        const f32x2 rd = rcpv(dA * e);
        cc = (cc * dA + t * e) * rd;
        const f32x2 C = exp2v(cc);
        // h = o*tanh(c) = (C-1) * rcp((C+1)(1+O))
        const f32x2 rr = rcpv((C + one) * (one + O));
        hh = (C - one) * rr;

        if (!last) {
            // packed RTZ convert: 1 inst vs cvt+cvt+pack (4B-aligned: hrow even)
            *(h16x2*)&bn[colh * BSTR + hrow] = __builtin_amdgcn_cvt_pkrtz(hh[0], hh[1]);
            __syncthreads();
        }
    };

    _Float16* b0 = &b_sh[0][0];
    _Float16* b1 = &b_sh[1][0];
    #pragma unroll 1
    for (int it = 0; it < TSTEPS / 2 - 1; ++it) {   // steps 0..125
        substep(2 * it,     b0, b1, false);
        substep(2 * it + 1, b1, b0, false);
        // loop-carried AGPR pins: block rematerialization (R1..R5 failure mode)
        asm volatile("" : "+a"(afr[0][0]), "+a"(afr[0][1]), "+a"(afr[0][2]), "+a"(afr[0][3]));
        asm volatile("" : "+a"(afr[1][0]), "+a"(afr[1][1]), "+a"(afr[1][2]), "+a"(afr[1][3]));
        asm volatile("" : "+a"(afr[2][0]), "+a"(afr[2][1]), "+a"(afr[2][2]), "+a"(afr[2][3]));
        asm volatile("" : "+a"(afr[3][0]), "+a"(afr[3][1]), "+a"(afr[3][2]), "+a"(afr[3][3]));
    }
    substep(126, b0, b1, false);
    substep(127, b1, b0, true);    // peeled: no h-write, no barrier

    // ---- final h -> LDS (fp32), then fused FC epilogue ----
    hbuf[colh * HSTR + hrow]     = hh[0];
    hbuf[colh * HSTR + hrow + 1] = hh[1];
    __syncthreads();

    if (!ball) {
        // player part: out[gp*40+row] += fc_b[row] + fc_w[row, 0:128] . h(gp)
        for (int o = tid; o < NB * 40; o += 512) {
            const int j = o / 40, row = o - j * 40;
            const float* wr = fc_w + (size_t)row * 2 * HDIM;        // cols 0..127
            const float* hp = &hbuf[j * HSTR];
            float a0 = fc_b[row], a1 = 0.f, a2 = 0.f, a3 = 0.f;
            #pragma unroll
            for (int k = 0; k < HDIM; k += 4) {
                float4 wv = *(const float4*)(wr + k);
                float4 hv = *(const float4*)(hp + k);
                a0 = __builtin_fmaf(wv.x, hv.x, a0);
                a1 = __builtin_fmaf(wv.y, hv.y, a1);
                a2 = __builtin_fmaf(wv.z, hv.z, a2);
                a3 = __builtin_fmaf(wv.w, hv.w, a3);
            }
            atomicAdd(&out[(size_t)(NB * blk + j) * 40 + row], (a0 + a1) + (a2 + a3));
        }
    } else {
        // ball part: v[c][row] = fc_w[row, 128:256] . ball_h(batch), then
        // broadcast-add to the batch's 22 players.
        for (int o = tid; o < NB * 40; o += 512) {
            const int c = o / 40, row = o - c * 40;
            const float* wr = fc_w + (size_t)row * 2 * HDIM + HDIM;  // cols 128..255
            const float* hp = &hbuf[c * HSTR];
            float a0 = 0.f, a1 = 0.f, a2 = 0.f, a3 = 0.f;
            #pragma unroll
            for (int k = 0; k < HDIM; k += 4) {
                float4 wv = *(const float4*)(wr + k);
                float4 hv = *(const float4*)(hp + k);
                a0 = __builtin_fmaf(wv.x, hv.x, a0);
                a1 = __builtin_fmaf(wv.y, hv.y, a1);
                a2 = __builtin_fmaf(wv.z, hv.z, a2);
                a3 = __builtin_fmaf(wv.w, hv.w, a3);
            }
            vout[c * 40 + row] = (a0 + a1) + (a2 + a3);
        }
        __syncthreads();
        const int base_batch = (blk - NPBLK) * NB;
        for (int o = tid; o < NB * 22 * 40; o += 512) {
            const int c = o / 880, rem = o - c * 880;
            const int p = rem / 40, row = rem - p * 40;
            atomicAdd(&out[(size_t)((base_batch + c) * 22 + p) * 40 + row],
                      vout[c * 40 + row]);
        }
    }
}

extern "C" void kernel_launch(void* const* d_in, const int* in_sizes, int n_in,
                              void* d_out, int out_size, void* d_ws, size_t ws_size,
                              hipStream_t stream) {
    const float* x_players = (const float*)d_in[0];
    const float* x_ball    = (const float*)d_in[1];
    const float* p_w_ih    = (const float*)d_in[2];
    const float* p_w_hh    = (const float*)d_in[3];
    const float* p_b_ih    = (const float*)d_in[4];
    const float* p_b_hh    = (const float*)d_in[5];
    const float* b_w_ih    = (const float*)d_in[6];
    const float* b_w_hh    = (const float*)d_in[7];
    const float* b_b_ih    = (const float*)d_in[8];
    const float* b_b_hh    = (const float*)d_in[9];
    const float* fc_w      = (const float*)d_in[10];
    const float* fc_b      = (const float*)d_in[11];

    // zero the output: both block types accumulate into it atomically
    hipMemsetAsync(d_out, 0, (size_t)out_size * sizeof(float), stream);

    lstm_fc_kernel<<<dim3(NBLK), dim3(512), 0, stream>>>(
        x_players, x_ball, p_w_ih, p_w_hh, p_b_ih, p_b_hh,
        b_w_ih, b_w_hh, b_b_ih, b_b_hh, fc_w, fc_b, (float*)d_out);
}